// Round 6
// baseline (356.541 us; speedup 1.0000x reference)
//
#include <hip/hip_runtime.h>

typedef _Float16 half_t;
typedef __attribute__((ext_vector_type(4))) _Float16 half4;
typedef __attribute__((ext_vector_type(8))) _Float16 half8;
typedef __attribute__((ext_vector_type(2))) float f32x2;
typedef __attribute__((ext_vector_type(4))) float f32x4;

#define NB 32
#define NH 128
#define NW 128
#define NOH 122
#define NOW 122
#define NOC 512
#define KPAD 64

// ws layout (bytes):
//   gh: [32][128][128] half  @ 0         (1048576)
//   Wh: [512][64]      half  @ 1048576   (65536)   t = kh*8+kw, zero-padded
//   w2: [512]          float @ 1114112   (2048)

__global__ __launch_bounds__(256) void k_gray(const float* __restrict__ x,
                                              half_t* __restrict__ gh) {
    int t = blockIdx.x * 256 + threadIdx.x;   // one thread = 4 pixels
    if (t >= NB * NH * NW / 4) return;
    int b = t >> 12;
    int pix4 = t & 4095;
    const float* xb = x + (size_t)b * 3 * 16384 + pix4 * 4;
    f32x4 r = *(const f32x4*)xb;
    f32x4 g = *(const f32x4*)(xb + 16384);
    f32x4 bl = *(const f32x4*)(xb + 32768);
    half4 o;
#pragma unroll
    for (int i = 0; i < 4; ++i)
        o[i] = (half_t)(0.2989f * r[i] + 0.587f * g[i] + 0.114f * bl[i]);
    *(half4*)(gh + (size_t)t * 4) = o;
}

__global__ __launch_bounds__(256) void k_w(const float* __restrict__ w,
                                           half_t* __restrict__ Wh,
                                           float* __restrict__ w2) {
    int o = blockIdx.x * 256 + threadIdx.x;
    if (o >= NOC) return;
    float s = 0.f;
    for (int t = 0; t < KPAD; ++t) {
        int kh = t >> 3, kw = t & 7;
        float v = (kh < 7 && kw < 7) ? w[o * 49 + kh * 7 + kw] : 0.f;
        half_t h = (half_t)v;
        Wh[o * KPAD + t] = h;
        float f = (float)h;
        s += f * f;
    }
    w2[o] = s;
}

// v6 main: 32 o x 2 oh x 128 p per block; x2 computed in-block from the staged
// gS rows (separable); result staged in LDS in exact global layout; flush =
// contiguous 976B per o. LDS ~38.7KB -> 4 blocks/CU for dephased store bursts.
__global__ __launch_bounds__(256, 4) void k_main(const half_t* __restrict__ gh,
                                                 const half_t* __restrict__ Wh,
                                                 const float* __restrict__ w2,
                                                 const float* __restrict__ stdp,
                                                 float* __restrict__ out) {
    const int fgg = blockIdx.x;   // 0..15  (32 filters)
    const int ohp = blockIdx.y;   // 0..60  (oh pair)
    const int b   = blockIdx.z;   // 0..31
    const int oh0 = ohp * 2;

    __shared__ half_t gS[9][136];       // rows oh0..oh0+8 (clamped), cols>=128 zero
    __shared__ float  rs2[8][124];      // rowsum of squares, rows oh0..oh0+7
    __shared__ float  x2L[2][124];      // x2 for oh0, oh0+1 (p>=122 zeroed)
    __shared__ float  outT[32 * 244];   // [o_local][lo*122 + p] == global layout

    const int tid  = threadIdx.x;
    const int wave = tid >> 6;
    const int lane = tid & 63;
    const int col  = lane & 15;
    const int kq   = lane >> 4;
    const int n0   = wave * 32;

    // Stage 9 input rows (row 8 only feeds zero-weight taps when oh0==120).
    for (int idx = tid; idx < 9 * 136; idx += 256) {
        int r = idx / 136;
        int c = idx - r * 136;
        int row = oh0 + r;
        if (row > NH - 1) row = NH - 1;
        gS[r][c] = (c < 128) ? gh[((size_t)b * NH + row) * NW + c] : (half_t)0.f;
    }

    // B (weights): o = fgg*32 + ni*16 + col, elem i -> tap (ks*4+kq)*8 + i.
    half8 wfrag[2][2];
#pragma unroll
    for (int ni = 0; ni < 2; ++ni)
#pragma unroll
        for (int ks = 0; ks < 2; ++ks)
            wfrag[ni][ks] = *(const half8*)(Wh + ((size_t)(fgg * 32 + ni * 16 + col) * KPAD
                                                  + (ks * 4 + kq) * 8));
    float w2c[2];
#pragma unroll
    for (int ni = 0; ni < 2; ++ni) w2c[ni] = w2[fgg * 32 + ni * 16 + col];

    const float sv = stdp[0];
    const float inv2s2 = 0.5f / (sv * sv);

    __syncthreads();

    // rs2[r][p] = sum_{kw<7} gS[r][p+kw]^2  (8 rows x 122 p, padded map 8x128)
    for (int idx = tid; idx < 8 * 128; idx += 256) {
        int r = idx >> 7;
        int p = idx & 127;
        if (p < NOW) {
            float s = 0.f;
#pragma unroll
            for (int kw = 0; kw < 7; ++kw) {
                float v = (float)gS[r][p + kw];
                s += v * v;
            }
            rs2[r][p] = s;
        }
    }
    __syncthreads();

    // x2L[lo][p] = sum_{kh<7} rs2[lo+kh][p]; zero-pad p=122..123.
    if (tid < 256) {
        int lo = tid >> 7;
        int p = tid & 127;
        if (p < 124) {
            float s = 0.f;
            if (p < NOW) {
#pragma unroll
                for (int kh = 0; kh < 7; ++kh) s += rs2[lo + kh][p];
            }
            x2L[lo][p] = s;
        }
    }
    __syncthreads();

#pragma unroll
    for (int lo = 0; lo < 2; ++lo) {
        // A (window): row p = n0 + mi*16 + col, elem i -> gS[lo+ks*4+kq][p+i].
        half8 afrag[2][2];
#pragma unroll
        for (int mi = 0; mi < 2; ++mi) {
            const int p = n0 + mi * 16 + col;
#pragma unroll
            for (int ks = 0; ks < 2; ++ks) {
                const half_t* src = &gS[lo + ks * 4 + kq][p];
                half8 v;
#pragma unroll
                for (int i = 0; i < 8; ++i) v[i] = src[i];
                afrag[mi][ks] = v;
            }
        }

        f32x4 acc[2][2];
#pragma unroll
        for (int mi = 0; mi < 2; ++mi)
#pragma unroll
            for (int ni = 0; ni < 2; ++ni) {
                f32x4 z = {0.f, 0.f, 0.f, 0.f};
                acc[mi][ni] = z;
            }

#pragma unroll
        for (int ks = 0; ks < 2; ++ks)
#pragma unroll
            for (int mi = 0; mi < 2; ++mi)
#pragma unroll
                for (int ni = 0; ni < 2; ++ni)
                    acc[mi][ni] = __builtin_amdgcn_mfma_f32_16x16x32_f16(
                        afrag[mi][ks], wfrag[ni][ks], acc[mi][ni], 0, 0, 0);

        // Epilogue -> LDS tile (global layout). D: col -> o tile idx, kq*4+r -> p.
#pragma unroll
        for (int mi = 0; mi < 2; ++mi) {
            const int p0 = n0 + mi * 16 + kq * 4;
            if (p0 >= NOW) continue;                   // p0==124 idle
            const f32x4 x2v = *(const f32x4*)(&x2L[lo][p0]);
            const bool full = (p0 + 3 < NOW);          // p0==120 -> 2 valid
#pragma unroll
            for (int ni = 0; ni < 2; ++ni) {
                f32x4 res;
#pragma unroll
                for (int r = 0; r < 4; ++r) {
                    float sq = fmaxf(fmaf(-2.f, acc[mi][ni][r], x2v[r] + w2c[ni]), 0.f);
                    res[r] = __expf(-sq * inv2s2);
                }
                float* dst = &outT[(ni * 16 + col) * 244 + lo * 122 + p0];
                f32x2 lo2 = {res[0], res[1]};
                *(f32x2*)dst = lo2;
                if (full) {
                    f32x2 hi2 = {res[2], res[3]};
                    *(f32x2*)(dst + 2) = hi2;
                }
            }
        }
    }

    __syncthreads();

    // Flush: 32 chunks of 976B contiguous; wave w owns chunks w*8..w*8+7.
    if (lane < 61) {
        const size_t base = (((size_t)b * NOC + fgg * 32) * NOH + oh0) * NOW;
#pragma unroll 4
        for (int c = 0; c < 8; ++c) {
            const int o = wave * 8 + c;
            f32x4 v = *(const f32x4*)&outT[o * 244 + lane * 4];   // 16B aligned
            *(f32x4*)(out + base + (size_t)o * NOH * NOW + lane * 4) = v;
        }
    }
}

extern "C" void kernel_launch(void* const* d_in, const int* in_sizes, int n_in,
                              void* d_out, int out_size, void* d_ws, size_t ws_size,
                              hipStream_t stream) {
    const float* x    = (const float*)d_in[0];
    const float* w    = (const float*)d_in[1];
    const float* stdp = (const float*)d_in[2];
    float* out = (float*)d_out;

    char* ws = (char*)d_ws;
    half_t* gh = (half_t*)ws;
    half_t* Wh = (half_t*)(ws + 1048576);
    float*  w2 = (float*)(ws + 1114112);

    k_gray<<<(NB * NH * NW / 4 + 255) / 256, 256, 0, stream>>>(x, gh);
    k_w<<<(NOC + 255) / 256, 256, 0, stream>>>(w, Wh, w2);

    dim3 grid(16, 61, NB);
    k_main<<<grid, 256, 0, stream>>>(gh, Wh, w2, stdp, out);
}

// Round 7
// 302.292 us; speedup vs baseline: 1.1795x; 1.1795x over previous
//
#include <hip/hip_runtime.h>

typedef _Float16 half_t;
typedef __attribute__((ext_vector_type(4))) _Float16 half4;
typedef __attribute__((ext_vector_type(8))) _Float16 half8;
typedef __attribute__((ext_vector_type(2))) float f32x2;
typedef __attribute__((ext_vector_type(4))) float f32x4;

#define NB 32
#define NH 128
#define NW 128
#define NOH 122
#define NOW 122
#define NOC 512
#define KPAD 64

// ws layout (bytes):
//   gh: [32][128][128] half  @ 0         (1048576)
//   Wh: [512][64]      half  @ 1048576   (65536)   t = kh*8+kw, zero-padded
//   w2: [512]          float @ 1114112   (2048)
//   x2: [32][122][122] float @ 1116160   (1905152 + 128 slack)
//   Sg: [32][128][122] float @ 3021440   (1998848)

__global__ __launch_bounds__(256) void k_gray(const float* __restrict__ x,
                                              half_t* __restrict__ gh) {
    int t = blockIdx.x * 256 + threadIdx.x;   // one thread = 4 pixels
    if (t >= NB * NH * NW / 4) return;
    int b = t >> 12;
    int pix4 = t & 4095;
    const float* xb = x + (size_t)b * 3 * 16384 + pix4 * 4;
    f32x4 r = *(const f32x4*)xb;
    f32x4 g = *(const f32x4*)(xb + 16384);
    f32x4 bl = *(const f32x4*)(xb + 32768);
    half4 o;
#pragma unroll
    for (int i = 0; i < 4; ++i)
        o[i] = (half_t)(0.2989f * r[i] + 0.587f * g[i] + 0.114f * bl[i]);
    *(half4*)(gh + (size_t)t * 4) = o;
}

__global__ __launch_bounds__(256) void k_w(const float* __restrict__ w,
                                           half_t* __restrict__ Wh,
                                           float* __restrict__ w2) {
    int o = blockIdx.x * 256 + threadIdx.x;
    if (o >= NOC) return;
    float s = 0.f;
    for (int t = 0; t < KPAD; ++t) {
        int kh = t >> 3, kw = t & 7;
        float v = (kh < 7 && kw < 7) ? w[o * 49 + kh * 7 + kw] : 0.f;
        half_t h = (half_t)v;
        Wh[o * KPAD + t] = h;
        float f = (float)h;
        s += f * f;
    }
    w2[o] = s;
}

// Sg[b][h][p] = sum_{kw<7} gh[b][h][p+kw]^2   (separable pass 1)
__global__ __launch_bounds__(256) void k_rs(const half_t* __restrict__ gh,
                                            float* __restrict__ Sg) {
    int t = blockIdx.x * 256 + threadIdx.x;
    if (t >= NB * NH * NOW) return;
    int b = t / (NH * NOW);
    int rem = t - b * (NH * NOW);
    int h = rem / NOW;
    int p = rem - h * NOW;
    const half_t* g = gh + ((size_t)b * NH + h) * NW + p;
    float s = 0.f;
#pragma unroll
    for (int kw = 0; kw < 7; ++kw) {
        float v = (float)g[kw];
        s += v * v;
    }
    Sg[t] = s;
}

// x2[b][oh][p] = sum_{kh<7} Sg[b][oh+kh][p]   (separable pass 2)
__global__ __launch_bounds__(256) void k_x2(const float* __restrict__ Sg,
                                            float* __restrict__ x2) {
    int t = blockIdx.x * 256 + threadIdx.x;
    if (t >= NB * NOH * NOW) return;
    int b = t / (NOH * NOW);
    int rem = t - b * (NOH * NOW);
    int oh = rem / NOW;
    int p = rem - oh * NOW;
    const float* s0 = Sg + ((size_t)b * NH + oh) * NOW + p;
    float s = 0.f;
#pragma unroll
    for (int kh = 0; kh < 7; ++kh) s += s0[kh * NOW];
    x2[t] = s;
}

// v7 main: 32 o x 4 oh x 122 p per block -> 1952B contiguous chunk per o.
// Grid x = oh-quad (fastest) so concurrent XCDs write consecutive chunks of
// the same o (DRAM row locality). Flush uses non-temporal stores (write-once
// data, keep L2 for the read side). Tail quad overlaps (identical re-write).
__global__ __launch_bounds__(256, 2) void k_main(const half_t* __restrict__ gh,
                                                 const half_t* __restrict__ Wh,
                                                 const float* __restrict__ w2,
                                                 const float* __restrict__ x2,
                                                 const float* __restrict__ stdp,
                                                 float* __restrict__ out) {
    const int ohq = blockIdx.x;   // 0..30 (oh quad, fastest-varying)
    const int fgg = blockIdx.y;   // 0..15 (32 filters)
    const int b   = blockIdx.z;   // 0..31
    const int oh0 = (ohq * 4 > NOH - 4) ? (NOH - 4) : (ohq * 4);  // 118 max

    __shared__ half_t gS[11][136];      // rows oh0..oh0+10 (clamped), cols>=128 zero
    __shared__ float  outT[32 * 488];   // [o_local][lo*122 + p] == global layout

    const int tid  = threadIdx.x;
    const int wave = tid >> 6;
    const int lane = tid & 63;
    const int col  = lane & 15;
    const int kq   = lane >> 4;
    const int n0   = wave * 32;

    // Stage 11 input rows (row idx 10 only feeds zero-weight kh==7 taps when
    // oh0==118; clamp keeps it finite).
    for (int idx = tid; idx < 11 * 136; idx += 256) {
        int r = idx / 136;
        int c = idx - r * 136;
        int row = oh0 + r;
        if (row > NH - 1) row = NH - 1;
        gS[r][c] = (c < 128) ? gh[((size_t)b * NH + row) * NW + c] : (half_t)0.f;
    }

    // B (weights): o = fgg*32 + ni*16 + col, elem i -> tap (ks*4+kq)*8 + i.
    half8 wfrag[2][2];
#pragma unroll
    for (int ni = 0; ni < 2; ++ni)
#pragma unroll
        for (int ks = 0; ks < 2; ++ks)
            wfrag[ni][ks] = *(const half8*)(Wh + ((size_t)(fgg * 32 + ni * 16 + col) * KPAD
                                                  + (ks * 4 + kq) * 8));
    float w2c[2];
#pragma unroll
    for (int ni = 0; ni < 2; ++ni) w2c[ni] = w2[fgg * 32 + ni * 16 + col];

    const float sv = stdp[0];
    const float inv2s2 = 0.5f / (sv * sv);

    __syncthreads();

#pragma unroll
    for (int lo = 0; lo < 4; ++lo) {
        const int oh = oh0 + lo;

        // A (window): row p = n0 + mi*16 + col, elem i -> gS[lo+ks*4+kq][p+i].
        half8 afrag[2][2];
#pragma unroll
        for (int mi = 0; mi < 2; ++mi) {
            const int p = n0 + mi * 16 + col;
#pragma unroll
            for (int ks = 0; ks < 2; ++ks) {
                const half_t* src = &gS[lo + ks * 4 + kq][p];
                half8 v;
#pragma unroll
                for (int i = 0; i < 8; ++i) v[i] = src[i];
                afrag[mi][ks] = v;
            }
        }

        f32x4 acc[2][2];
#pragma unroll
        for (int mi = 0; mi < 2; ++mi)
#pragma unroll
            for (int ni = 0; ni < 2; ++ni) {
                f32x4 z = {0.f, 0.f, 0.f, 0.f};
                acc[mi][ni] = z;
            }

#pragma unroll
        for (int ks = 0; ks < 2; ++ks)
#pragma unroll
            for (int mi = 0; mi < 2; ++mi)
#pragma unroll
                for (int ni = 0; ni < 2; ++ni)
                    acc[mi][ni] = __builtin_amdgcn_mfma_f32_16x16x32_f16(
                        afrag[mi][ks], wfrag[ni][ks], acc[mi][ni], 0, 0, 0);

        const size_t rowBase = ((size_t)b * NOH + oh) * NOW;

        // Epilogue -> LDS tile (global layout). D: col -> o tile idx, kq*4+r -> p.
#pragma unroll
        for (int mi = 0; mi < 2; ++mi) {
            const int p0 = n0 + mi * 16 + kq * 4;
            if (p0 >= NOW) continue;                   // p0==124 idle
            const f32x4 x2v = *(const f32x4*)(x2 + rowBase + p0);
            const bool full = (p0 + 3 < NOW);          // p0==120 -> 2 valid
#pragma unroll
            for (int ni = 0; ni < 2; ++ni) {
                f32x4 res;
#pragma unroll
                for (int r = 0; r < 4; ++r) {
                    float sq = fmaxf(fmaf(-2.f, acc[mi][ni][r], x2v[r] + w2c[ni]), 0.f);
                    res[r] = __expf(-sq * inv2s2);
                }
                float* dst = &outT[(ni * 16 + col) * 488 + lo * 122 + p0];
                f32x2 lo2 = {res[0], res[1]};
                *(f32x2*)dst = lo2;
                if (full) {
                    f32x2 hi2 = {res[2], res[3]};
                    *(f32x2*)(dst + 2) = hi2;
                }
            }
        }
    }

    __syncthreads();

    // Flush: 32 chunks of 1952B contiguous; wave w owns chunks w*8..w*8+7.
    // Non-temporal: write-once data, don't churn L2.
    if (lane < 61) {
        const size_t base = (((size_t)b * NOC + fgg * 32) * NOH + oh0) * NOW;
#pragma unroll 4
        for (int c = 0; c < 8; ++c) {
            const int o = wave * 8 + c;
            float* gdst = out + base + (size_t)o * NOH * NOW + lane * 4;
#pragma unroll
            for (int j = 0; j < 2; ++j) {
                f32x4 v = *(const f32x4*)&outT[o * 488 + j * 244 + lane * 4];
                __builtin_nontemporal_store(v, (f32x4*)(gdst + j * 244));
            }
        }
    }
}

extern "C" void kernel_launch(void* const* d_in, const int* in_sizes, int n_in,
                              void* d_out, int out_size, void* d_ws, size_t ws_size,
                              hipStream_t stream) {
    const float* x    = (const float*)d_in[0];
    const float* w    = (const float*)d_in[1];
    const float* stdp = (const float*)d_in[2];
    float* out = (float*)d_out;

    char* ws = (char*)d_ws;
    half_t* gh = (half_t*)ws;
    half_t* Wh = (half_t*)(ws + 1048576);
    float*  w2 = (float*)(ws + 1114112);
    float*  x2 = (float*)(ws + 1116160);
    float*  Sg = (float*)(ws + 3021440);

    k_gray<<<(NB * NH * NW / 4 + 255) / 256, 256, 0, stream>>>(x, gh);
    k_w<<<(NOC + 255) / 256, 256, 0, stream>>>(w, Wh, w2);
    k_rs<<<(NB * NH * NOW + 255) / 256, 256, 0, stream>>>(gh, Sg);
    k_x2<<<(NB * NOH * NOW + 255) / 256, 256, 0, stream>>>(Sg, x2);

    dim3 grid(31, 16, NB);
    k_main<<<grid, 256, 0, stream>>>(gh, Wh, w2, x2, stdp, out);
}